// Round 10
// baseline (2739.238 us; speedup 1.0000x reference)
//
#include <hip/hip_runtime.h>
#include <hip/hip_cooperative_groups.h>
#include <cmath>

namespace cg = cooperative_groups;

namespace {

constexpr int B = 16, C = 3, H = 768, W = 768;
constexpr int HW = H * W;
constexpr int BC = B * C;
constexpr int NDROPS = 10;
constexpr int KS[NDROPS] = {23, 37, 13, 23, 13, 33, 25, 27, 15, 21};
constexpr float BLUR_R[NDROPS] = {11.3535f, 17.9381f, 5.7966f, 10.8586f, 5.5301f,
                                  15.9075f, 12.3225f, 13.4871f, 6.6639f, 9.5413f};
constexpr int MAXK = 37;
constexpr int MAXP = MAXK / 2;  // 18

// mask < ~8.6e-8 outside d > SFAC^2 (d^1.8 > 16.2): composite == prev there.
constexpr float SFAC = 2.17f;
constexpr int BOXW = 384;            // >= 2*2.17*80 = 348
constexpr int BOXH = 288;            // >= 2*2.17*64 = 278
constexpr int YT = 32;               // output rows per blur tile
constexpr int MH = BOXH + 2 * MAXP;  // 324
constexpr int MW = 448;              // mask box cols
constexpr int NXT = BOXW / 64;       // 6
constexpr int NYT = BOXH / YT;       // 9
constexpr int NTILES = NXT * NYT * BC;  // 2592

// Fixed LDS strides sized for MAXK (shared across all K specializations).
constexpr int PSTR = 64 + MAXK - 1 + 2;  // 102 (even: 8B-aligned float2 rows)
constexpr int VSTR = 64 + MAXK - 1 + 1;  // 101 (odd: bank spread)
constexpr int PROWS = YT + MAXK - 1;     // 68

struct AllW {
    float w[NDROPS][MAXK];
};

}  // namespace

__device__ inline int refl(int v, int n) {
    return v < 0 ? -v : (v >= n ? 2 * n - 2 - v : v);
}

__device__ inline void drop_params(const float* __restrict__ pos,
                                   const float* __restrict__ rad, int j,
                                   float& x0, float& y0, float& wr, float& hr) {
    float px = fminf(fmaxf(pos[2 * j + 0], -1.f), 1.f);
    float py = fminf(fmaxf(pos[2 * j + 1], -1.f), 1.f);
    wr = fminf(fmaxf(rad[j], 60.f), 80.f);
    x0 = (px + 1.f) * 0.5f * (float)W;
    y0 = (py + 1.f) * 0.5f * (float)H;
    hr = wr * 0.8f;
}

__device__ inline void drop_box(const float* __restrict__ pos,
                                const float* __restrict__ rad, int j,
                                int& bx0, int& by0) {
    float x0, y0, wr, hr;
    drop_params(pos, rad, j, x0, y0, wr, hr);
    bx0 = max(0, (int)floorf(x0 - SFAC * wr));
    by0 = max(0, (int)floorf(y0 - SFAC * hr));
}

// ---------------------------------------------------------------------------
// One drop: blur phase (tiles -> stage), grid.sync, composite phase, grid.sync.
// Tile math identical to the audited round-8 fusedDrop/composite kernels.
// ---------------------------------------------------------------------------
template <int K>
__device__ void do_drop(const float* __restrict__ wrow,
                        const float* __restrict__ mb, float* __restrict__ out,
                        float* __restrict__ stage,
                        const float* __restrict__ pos,
                        const float* __restrict__ rad, int j,
                        float* __restrict__ prod_s, float* __restrict__ vbl_s) {
    constexpr int P = K / 2;
    constexpr int TC = 64 + K - 1;  // <= 100
    constexpr int TR = YT + K - 1;  // <= 68
    int bx0, by0;
    drop_box(pos, rad, j, bx0, by0);
    const int tx = threadIdx.x, ty = threadIdx.y;

    // ---- BLUR: persistent tile loop, write blurred box into stage ----
    for (int tile = blockIdx.x; tile < NTILES; tile += gridDim.x) {
        int xt = tile % NXT;
        int r6 = tile / NXT;
        int yt = r6 % NYT;
        int bc = r6 / NYT;
        int xb = xt * 64, yb = yt * YT;
        const float* op = out + (size_t)bc * HW;

        // Phase A: prod = out[refl]*mask (reflect + mask once per pixel)
        for (int cc = tx; cc < TC; cc += 64) {
            int rx = refl(bx0 + xb - P + cc, W);
            int xim = xb + cc + (MAXP - P);
            for (int r = ty; r < TR; r += 4) {
                int ry = refl(by0 + yb - P + r, H);
                prod_s[r * PSTR + cc] =
                    op[ry * W + rx] * mb[(yb + r + (MAXP - P)) * MW + xim];
            }
        }
        __syncthreads();

        // Phase B: vertical blur (float2 cols, 8-row sliding coarsen)
        {
            int c0 = 2 * tx;
            int base = ty * 8;
            if (c0 < TC) {
                float a0[8] = {0, 0, 0, 0, 0, 0, 0, 0};
                float a1[8] = {0, 0, 0, 0, 0, 0, 0, 0};
#pragma unroll
                for (int t = 0; t < K + 7; ++t) {
                    float2 v = *(const float2*)&prod_s[(base + t) * PSTR + c0];
#pragma unroll
                    for (int o = 0; o < 8; ++o) {
                        int ti = t - o;
                        if (ti >= 0 && ti < K) {
                            a0[o] += wrow[ti] * v.x;
                            a1[o] += wrow[ti] * v.y;
                        }
                    }
                }
#pragma unroll
                for (int o = 0; o < 8; ++o) {
                    vbl_s[(base + o) * VSTR + c0] = a0[o];
                    vbl_s[(base + o) * VSTR + c0 + 1] = a1[o];
                }
            }
        }
        __syncthreads();

        // Phase C: horizontal blur (8-col sliding coarsen), float4 stores
        {
            int tid = ty * 64 + tx;
            int xq = (tid & 7) * 8;
            int yi = tid >> 3;
            float acc[8] = {0, 0, 0, 0, 0, 0, 0, 0};
#pragma unroll
            for (int t = 0; t < K + 7; ++t) {
                float v = vbl_s[yi * VSTR + xq + t];
#pragma unroll
                for (int o = 0; o < 8; ++o) {
                    int ti = t - o;
                    if (ti >= 0 && ti < K) acc[o] += wrow[ti] * v;
                }
            }
            float* srow =
                stage + ((size_t)bc * BOXH + (yb + yi)) * BOXW + (xb + xq);
            *(float4*)&srow[0] = make_float4(acc[0], acc[1], acc[2], acc[3]);
            *(float4*)&srow[4] = make_float4(acc[4], acc[5], acc[6], acc[7]);
        }
        __syncthreads();  // LDS reuse guard before next tile's phase A
    }
    cg::this_grid().sync();

    // ---- COMPOSITE: out = stage*m + out*(1-m), own-pixel RMW ----
    for (int tile = blockIdx.x; tile < NTILES; tile += gridDim.x) {
        int xt = tile % NXT;
        int r6 = tile / NXT;
        int yt = r6 % NYT;
        int bc = r6 / NYT;
        int ci = xt * 64 + tx;
        int x = bx0 + ci;
        if (x < W) {
#pragma unroll
            for (int o = 0; o < 8; ++o) {
                int yi = yt * YT + ty * 8 + o;
                int y = by0 + yi;
                if (y < H) {
                    float m = mb[(size_t)(yi + MAXP) * MW + (ci + MAXP)];
                    float s = stage[((size_t)bc * BOXH + yi) * BOXW + ci];
                    size_t oo = (size_t)bc * HW + (size_t)y * W + x;
                    out[oo] = s * m + out[oo] * (1.f - m);
                }
            }
        }
    }
    cg::this_grid().sync();
}

// ---------------------------------------------------------------------------
// Persistent cooperative kernel: copy + masks + 10 drops, 21 grid syncs.
// ---------------------------------------------------------------------------
__global__ __launch_bounds__(256) void condensation_all(
    const float* __restrict__ img, const float* __restrict__ pos,
    const float* __restrict__ rad, float* __restrict__ out,
    float* __restrict__ mbox, float* __restrict__ stage, AllW allw) {
    __shared__ float prod_s[PROWS * PSTR];  // 27.7 KB
    __shared__ float vbl_s[YT * VSTR];      // 12.9 KB

    const int tid = threadIdx.y * 64 + threadIdx.x;
    const int gtid = blockIdx.x * 256 + tid;
    const int gstride = gridDim.x * 256;

    // Prologue 1: out = img (float4 grid-stride copy)
    {
        const float4* s4 = (const float4*)img;
        float4* d4 = (float4*)out;
        for (int i = gtid; i < BC * HW / 4; i += gstride) d4[i] = s4[i];
    }
    // Prologue 2: compact masks with reflection baked in
    for (int idx = gtid; idx < NDROPS * MH * MW; idx += gstride) {
        int j = idx / (MH * MW);
        int rem = idx - j * (MH * MW);
        int yi = rem / MW;
        int xi = rem - yi * MW;
        int bx0, by0;
        drop_box(pos, rad, j, bx0, by0);
        float x0, y0, wr, hr;
        drop_params(pos, rad, j, x0, y0, wr, hr);
        int rx = refl(bx0 - MAXP + xi, W);
        int ry = refl(by0 - MAXP + yi, H);
        float dy = (float)ry - y0;
        float dx = (float)rx - x0;
        float d = dy * dy / (hr * hr) + dx * dx / (wr * wr);
        float m = expf(-powf(d, 1.8f) + 1e-10f);
        m = fminf(fmaxf(m, 0.f), 1.f);
        mbox[idx] = m;
    }
    cg::this_grid().sync();

    do_drop<KS[0]>(allw.w[0], mbox + 0 * (size_t)MH * MW, out, stage, pos, rad, 0, prod_s, vbl_s);
    do_drop<KS[1]>(allw.w[1], mbox + 1 * (size_t)MH * MW, out, stage, pos, rad, 1, prod_s, vbl_s);
    do_drop<KS[2]>(allw.w[2], mbox + 2 * (size_t)MH * MW, out, stage, pos, rad, 2, prod_s, vbl_s);
    do_drop<KS[3]>(allw.w[3], mbox + 3 * (size_t)MH * MW, out, stage, pos, rad, 3, prod_s, vbl_s);
    do_drop<KS[4]>(allw.w[4], mbox + 4 * (size_t)MH * MW, out, stage, pos, rad, 4, prod_s, vbl_s);
    do_drop<KS[5]>(allw.w[5], mbox + 5 * (size_t)MH * MW, out, stage, pos, rad, 5, prod_s, vbl_s);
    do_drop<KS[6]>(allw.w[6], mbox + 6 * (size_t)MH * MW, out, stage, pos, rad, 6, prod_s, vbl_s);
    do_drop<KS[7]>(allw.w[7], mbox + 7 * (size_t)MH * MW, out, stage, pos, rad, 7, prod_s, vbl_s);
    do_drop<KS[8]>(allw.w[8], mbox + 8 * (size_t)MH * MW, out, stage, pos, rad, 8, prod_s, vbl_s);
    do_drop<KS[9]>(allw.w[9], mbox + 9 * (size_t)MH * MW, out, stage, pos, rad, 9, prod_s, vbl_s);
}

// ---------------------------------------------------------------------------
// Host side
// ---------------------------------------------------------------------------
static void make_weights(int j, float* w) {
    int K = KS[j];
    float sigma = BLUR_R[j];
    float half = (K - 1) * 0.5f;
    float sum = 0.f;
    for (int i = 0; i < K; ++i) {
        float xx = -half + (float)i;
        float v = xx / sigma;
        float p = expf(-0.5f * v * v);
        w[i] = p;
        sum += p;
    }
    for (int i = 0; i < K; ++i) w[i] /= sum;
    for (int i = K; i < MAXK; ++i) w[i] = 0.f;
}

extern "C" void kernel_launch(void* const* d_in, const int* in_sizes, int n_in,
                              void* d_out, int out_size, void* d_ws,
                              size_t ws_size, hipStream_t stream) {
    const float* img = (const float*)d_in[0];
    const float* pos = (const float*)d_in[1];
    const float* rad = (const float*)d_in[2];
    float* out = (float*)d_out;

    // ws: [mbox: 10*MH*MW f32 = 5.8MB][stage: BC*BOXH*BOXW f32 = 21.2MB]
    float* mbox = (float*)d_ws;
    float* stage = mbox + (size_t)NDROPS * MH * MW;

    AllW allw;
    for (int j = 0; j < NDROPS; ++j) make_weights(j, allw.w[j]);

    // Co-residency sizing (required for grid.sync): occupancy x CU count.
    int occ = 0;
    (void)hipOccupancyMaxActiveBlocksPerMultiprocessor(
        &occ, reinterpret_cast<const void*>(condensation_all), 256, 0);
    if (occ < 1) occ = 1;
    int dev = 0;
    (void)hipGetDevice(&dev);
    int cus = 256;  // MI355X default; query refines
    (void)hipDeviceGetAttribute(&cus, hipDeviceAttributeMultiprocessorCount, dev);
    long grid = (long)occ * (long)cus;
    if (grid > NTILES) grid = NTILES;

    void* args[] = {(void*)&img, (void*)&pos, (void*)&rad, (void*)&out,
                    (void*)&mbox, (void*)&stage, (void*)&allw};
    (void)hipLaunchCooperativeKernel(
        reinterpret_cast<const void*>(condensation_all), dim3((unsigned)grid),
        dim3(64, 4, 1), args, 0, stream);
}